// Round 6
// baseline (261.875 us; speedup 1.0000x reference)
//
#include <hip/hip_runtime.h>
#include <math.h>

#define NRREL 16
#define DDIM 128
#define BBATCH 4096
#define SNBR 64
#define ROWS 8

typedef __attribute__((ext_vector_type(8))) short short8;
typedef __attribute__((ext_vector_type(4))) float floatx4;

__device__ __forceinline__ unsigned short f2bf(float f) {
    unsigned u = __builtin_bit_cast(unsigned, f);
    u += 0x7fffu + ((u >> 16) & 1u);
    return (unsigned short)(u >> 16);
}
__device__ __forceinline__ float bf2f(unsigned short u) {
    return __builtin_bit_cast(float, ((unsigned)u) << 16);
}

// ============ prep: weight conversion only (256 blocks) ============
extern "C" __global__ __launch_bounds__(256)
void k_prep(const float* __restrict__ W_rgcn,
            const float* __restrict__ res_w, const float* __restrict__ proj_w,
            const float* __restrict__ in_w, const float* __restrict__ out_w,
            unsigned short* __restrict__ Wcat, unsigned short* __restrict__ resw,
            unsigned short* __restrict__ projw, unsigned short* __restrict__ inw,
            unsigned short* __restrict__ outw)
{
    __shared__ float tileT[64 * 65];
    const int bid = blockIdx.x, t = threadIdx.x;

    if (bid < 128) {
        // ---------------- Wcat transpose: 64k x 64e tile ----------------
        const int l = bid >> 6, rem = bid & 63;
        const int k0 = (rem >> 1) * 64, e0 = (rem & 1) * 64;
        #pragma unroll
        for (int i = 0; i < 4; ++i) {
            int flat = t + 256 * i;              // 64 k x 16 col4
            int k = flat >> 4, c = flat & 15;
            float4 v = *(const float4*)(W_rgcn + ((size_t)(l * 2048 + k0 + k)) * 128 + e0 + 4 * c);
            tileT[(4 * c + 0) * 65 + k] = v.x;
            tileT[(4 * c + 1) * 65 + k] = v.y;
            tileT[(4 * c + 2) * 65 + k] = v.z;
            tileT[(4 * c + 3) * 65 + k] = v.w;
        }
        __syncthreads();
        const int e = t >> 2, m = t & 3;
        #pragma unroll
        for (int half = 0; half < 2; ++half) {
            int kk = 16 * m + 8 * half;
            short8 o;
            #pragma unroll
            for (int j = 0; j < 8; ++j) o[j] = (short)f2bf(tileT[e * 65 + kk + j]);
            *(short8*)(Wcat + ((size_t)(l * 128 + e0 + e)) * 2048 + k0 + kk) = o;
        }
    } else {
        // ---------------- flat weight converts ----------------
        int j4 = ((bid - 128) * 256 + t) * 4;   // 131072 floats
        const float* src; unsigned short* dst; int off;
        if (j4 < 32768)       { src = res_w;  dst = resw;  off = j4; }
        else if (j4 < 65536)  { src = proj_w; dst = projw; off = j4 - 32768; }
        else if (j4 < 114688) { src = in_w;   dst = inw;   off = j4 - 65536; }
        else                  { src = out_w;  dst = outw;  off = j4 - 114688; }
        float4 v = *(const float4*)(src + off);
        ushort4 o = { f2bf(v.x), f2bf(v.y), f2bf(v.z), f2bf(v.w) };
        *(ushort4*)(dst + off) = o;
    }
}

// ====== fused, 8 rows/block, 512 blocks x 512 thr: LDS ~47KB -> 2-3 blocks/CU ======
extern "C" __global__ __launch_bounds__(512)
void k_fused(const int* __restrict__ drug, const int* __restrict__ adj_e,
             const int* __restrict__ adj_r, const float* __restrict__ ew,
             const float* __restrict__ emb,
             const unsigned short* __restrict__ Wcat,
             const unsigned short* __restrict__ resw, const unsigned short* __restrict__ projw,
             const float* __restrict__ res_b, const float* __restrict__ proj_b,
             const float* __restrict__ ln_g, const float* __restrict__ ln_b,
             const unsigned short* __restrict__ inw, const float* __restrict__ in_b,
             const unsigned short* __restrict__ outw, const float* __restrict__ out_b,
             const float* __restrict__ fg, const float* __restrict__ fb,
             float* __restrict__ outp)
{
    __shared__ union {
        struct { unsigned short preA[ROWS * 2056]; } a;   // 32.9 KB gather dest / msgs A
        struct {
            unsigned short h_b16[ROWS * 136];             // 2.1 KB
            unsigned short xs_l[2 * ROWS * 136];          // 4.3 KB
            unsigned short qkvl[2 * ROWS * 392];          // 12.5 KB
        } t;
    } sm;
    __shared__ float node_ln[ROWS * 132];                  // 4.2 KB
    __shared__ unsigned short node_b16[ROWS * 136];        // 2.1 KB
    __shared__ union {
        struct {
            int   cnt[ROWS][16];
            int   strt[ROWS][16];
            int   sperm[ROWS][64];
            float wperm[ROWS][64];
        } g;                                               // 5 KB
        float msum[ROWS * 260];                            // 8.3 KB
    } sg;
    __shared__ float psum[8][8], psq[8][8];

    const int t = threadIdx.x, w = t >> 6, lane = t & 63, l15 = lane & 15, q = lane >> 4;
    const int r0 = blockIdx.x * ROWS;

    // ---- phase A: each thread owns 1 edge; node rows into LDS ----
    const int erow = t >> 6, es = t & 63;
    int   ent0 = adj_e[(r0 + erow) * SNBR + es];
    float ewt0 = ew[(r0 + erow) * SNBR + es];
    int   rel0 = adj_r[(r0 + erow) * SNBR + es];
    if (t < 128) sg.g.cnt[t >> 4][t & 15] = 0;
    if (t < 256) {
        int rr = t >> 5, c = t & 31;         // 8 rows x 32 col4
        int di = drug[r0 + rr];
        float4 v = *(const float4*)(emb + (size_t)di * DDIM + 4 * c);
        *(float4*)(node_ln + rr * 132 + 4 * c) = v;
        ushort4 o = { f2bf(v.x), f2bf(v.y), f2bf(v.z), f2bf(v.w) };
        *(ushort4*)(node_b16 + rr * 136 + 4 * c) = o;
    }
    __syncthreads();

    // ---- phase B: count members per (row, rel) ----
    atomicAdd(&sg.g.cnt[erow][rel0], 1);
    __syncthreads();

    // ---- phase C: prefix sums (CSR starts) ----
    if (t < ROWS) {
        int a = 0;
        #pragma unroll
        for (int r = 0; r < NRREL; ++r) { sg.g.strt[t][r] = a; a += sg.g.cnt[t][r]; }
    }
    __syncthreads();

    // ---- phase D: place (entity, weight) bucket-sorted; strt becomes end ----
    {
        int pos0 = atomicAdd(&sg.g.strt[erow][rel0], 1);
        sg.g.sperm[erow][pos0] = ent0;
        sg.g.wperm[erow][pos0] = ewt0;
    }
    __syncthreads();

    // ---- phase E: accumulate preA; 4 units/thread, batch-8 loads in flight ----
    {
        #pragma unroll 1
        for (int i = 0; i < 4; ++i) {
            int u = t + 512 * i;                 // 8 rows x 16 rel x 16 g8 = 2048
            int row = u >> 8, rl = (u >> 4) & 15, g8 = u & 15;
            int n = sg.g.cnt[row][rl];
            int end = sg.g.strt[row][rl];
            int beg = end - n;
            float acc[8] = {0.f, 0.f, 0.f, 0.f, 0.f, 0.f, 0.f, 0.f};
            #pragma unroll 1
            for (int jb = beg; jb < end; jb += 8) {
                const float* pp[8]; float wq[8];
                #pragma unroll
                for (int u2 = 0; u2 < 8; ++u2) {
                    int live = (jb + u2 < end);
                    int j = live ? jb + u2 : beg;
                    wq[u2] = live ? sg.g.wperm[row][j] : 0.f;
                    pp[u2] = emb + (size_t)sg.g.sperm[row][j] * DDIM + 8 * g8;
                }
                float4 v0[8], v1[8];
                #pragma unroll
                for (int u2 = 0; u2 < 8; ++u2) {
                    v0[u2] = *(const float4*)pp[u2];
                    v1[u2] = *(const float4*)(pp[u2] + 4);
                }
                #pragma unroll
                for (int u2 = 0; u2 < 8; ++u2) {
                    acc[0] = fmaf(v0[u2].x, wq[u2], acc[0]); acc[1] = fmaf(v0[u2].y, wq[u2], acc[1]);
                    acc[2] = fmaf(v0[u2].z, wq[u2], acc[2]); acc[3] = fmaf(v0[u2].w, wq[u2], acc[3]);
                    acc[4] = fmaf(v1[u2].x, wq[u2], acc[4]); acc[5] = fmaf(v1[u2].y, wq[u2], acc[5]);
                    acc[6] = fmaf(v1[u2].z, wq[u2], acc[6]); acc[7] = fmaf(v1[u2].w, wq[u2], acc[7]);
                }
            }
            short8 o;
            #pragma unroll
            for (int jj = 0; jj < 8; ++jj) o[jj] = (short)f2bf(acc[jj]);
            *(short8*)(sm.a.preA + row * 2056 + rl * DDIM + 8 * g8) = o;
        }
    }
    __syncthreads();

    // ---- msgs = preA[8,2048] x Wcat^T[2048,256]; wave w owns 32 cols ----
    {
        floatx4 macc[2] = {};
        const unsigned short* ap = sm.a.preA + (l15 & 7) * 2056 + 8 * q;
        const unsigned short* bp = Wcat + (size_t)(32 * w + l15) * 2048 + 8 * q;
        #pragma unroll 8
        for (int k = 0; k < 2048; k += 32) {
            short8 A = *(const short8*)(ap + k);
            #pragma unroll
            for (int ni = 0; ni < 2; ++ni) {
                short8 B = *(const short8*)(bp + (size_t)(ni * 16) * 2048 + k);
                macc[ni] = __builtin_amdgcn_mfma_f32_16x16x32_bf16(A, B, macc[ni], 0, 0, 0);
            }
        }
        if (q < 2) {
            #pragma unroll
            for (int ni = 0; ni < 2; ++ni) {
                int gc = 32 * w + ni * 16 + l15;
                #pragma unroll
                for (int r = 0; r < 4; ++r)
                    sg.msum[(4 * q + r) * 260 + gc] = macc[ni][r];
            }
        }
    }
    __syncthreads();          // preA dead; sm.t alive; gather scratch dead (msum alive)

    // ---- RGCN layers: wave w owns cols 16w..16w+15, rows 0..7 ----
    for (int l = 0; l < 2; ++l) {
        {   // GEMM1: h = relu(node + msum_l + node x resw_l^T + res_b)
            const unsigned short* Bw = resw + (size_t)l * DDIM * DDIM;
            floatx4 acc = {};
            const unsigned short* ap = node_b16 + (l15 & 7) * 136 + 8 * q;
            #pragma unroll
            for (int kk = 0; kk < DDIM; kk += 32) {
                short8 A = *(const short8*)(ap + kk);
                short8 B = *(const short8*)(Bw + (size_t)(16 * w + l15) * DDIM + kk + 8 * q);
                acc = __builtin_amdgcn_mfma_f32_16x16x32_bf16(A, B, acc, 0, 0, 0);
            }
            int gc = 16 * w + l15;
            float rb = res_b[l * DDIM + gc];
            if (q < 2) {
                #pragma unroll
                for (int r = 0; r < 4; ++r) {
                    int lr = 4 * q + r;
                    float v = acc[r] + rb + node_ln[lr * 132 + gc] + sg.msum[lr * 260 + l * DDIM + gc];
                    sm.t.h_b16[lr * 136 + gc] = f2bf(v > 0.f ? v : 0.f);
                }
            }
        }
        __syncthreads();
        {   // GEMM2 + LN
            const unsigned short* Bw = projw + (size_t)l * DDIM * DDIM;
            floatx4 acc = {};
            const unsigned short* ap = sm.t.h_b16 + (l15 & 7) * 136 + 8 * q;
            #pragma unroll
            for (int kk = 0; kk < DDIM; kk += 32) {
                short8 A = *(const short8*)(ap + kk);
                short8 B = *(const short8*)(Bw + (size_t)(16 * w + l15) * DDIM + kk + 8 * q);
                acc = __builtin_amdgcn_mfma_f32_16x16x32_bf16(A, B, acc, 0, 0, 0);
            }
            int gc = 16 * w + l15;
            float vv[4];
            float s4[4] = {0, 0, 0, 0}, sq4[4] = {0, 0, 0, 0};
            float pb = proj_b[l * DDIM + gc];
            if (q < 2) {
                #pragma unroll
                for (int r = 0; r < 4; ++r) {
                    float v = acc[r] + pb + node_ln[(4 * q + r) * 132 + gc];
                    vv[r] = v; s4[r] = v; sq4[r] = v * v;
                }
            }
            #pragma unroll
            for (int r = 0; r < 4; ++r)
                #pragma unroll
                for (int off2 = 8; off2 >= 1; off2 >>= 1) {
                    s4[r] += __shfl_xor(s4[r], off2, 64);
                    sq4[r] += __shfl_xor(sq4[r], off2, 64);
                }
            if (l15 == 0 && q < 2) {
                #pragma unroll
                for (int r = 0; r < 4; ++r) {
                    psum[w][4 * q + r] = s4[r];
                    psq[w][4 * q + r] = sq4[r];
                }
            }
            __syncthreads();
            float g2 = ln_g[l * DDIM + gc], bb = ln_b[l * DDIM + gc];
            if (q < 2) {
                #pragma unroll
                for (int r = 0; r < 4; ++r) {
                    int lr = 4 * q + r;
                    float ssum = 0.f, ssq = 0.f;
                    #pragma unroll
                    for (int ww = 0; ww < 8; ++ww) { ssum += psum[ww][lr]; ssq += psq[ww][lr]; }
                    float mean = ssum * (1.f / DDIM);
                    float var = ssq * (1.f / DDIM) - mean * mean;
                    float val = (vv[r] - mean) * rsqrtf(var + 1e-5f) * g2 + bb;
                    node_ln[lr * 132 + gc] = val;
                    unsigned short ub = f2bf(val);
                    node_b16[lr * 136 + gc] = ub;
                    sm.t.xs_l[(2 * lr + l) * 136 + gc] = ub;
                }
            }
            __syncthreads();
        }
    }

    // ---- qkv: A = xs_l[16 rows]; wave w owns 48 cols ----
    {
        floatx4 acc[3] = {};
        const unsigned short* ap = sm.t.xs_l + l15 * 136 + 8 * q;
        #pragma unroll
        for (int kk = 0; kk < DDIM; kk += 32) {
            short8 A = *(const short8*)(ap + kk);
            #pragma unroll
            for (int ni = 0; ni < 3; ++ni) {
                short8 B = *(const short8*)(inw + (size_t)(48 * w + ni * 16 + l15) * DDIM + kk + 8 * q);
                acc[ni] = __builtin_amdgcn_mfma_f32_16x16x32_bf16(A, B, acc[ni], 0, 0, 0);
            }
        }
        #pragma unroll
        for (int ni = 0; ni < 3; ++ni) {
            int gc = 48 * w + ni * 16 + l15;
            float ib = in_b[gc];
            #pragma unroll
            for (int r = 0; r < 4; ++r)
                sm.t.qkvl[(4 * q + r) * 392 + gc] = f2bf(acc[ni][r] + ib);
        }
    }
    __syncthreads();

    // ---- attention: 8 batch rows x 8 lanes (t < 64) ----
    if (t < 64) {
        int g4 = t >> 3, j = t & 7;
        const unsigned short* row0 = sm.t.qkvl + (2 * g4) * 392;
        const unsigned short* row1 = row0 + 392;
        float p00 = 0.f, p01 = 0.f, p10 = 0.f, p11 = 0.f;
        #pragma unroll
        for (int dd = 0; dd < 16; ++dd) {
            int d = 16 * j + dd;
            float q0 = bf2f(row0[d]), k0 = bf2f(row0[128 + d]);
            float q1 = bf2f(row1[d]), k1 = bf2f(row1[128 + d]);
            p00 = fmaf(q0, k0, p00); p01 = fmaf(q0, k1, p01);
            p10 = fmaf(q1, k0, p10); p11 = fmaf(q1, k1, p11);
        }
        p00 += __shfl_xor(p00, 1, 64); p01 += __shfl_xor(p01, 1, 64);
        p10 += __shfl_xor(p10, 1, 64); p11 += __shfl_xor(p11, 1, 64);
        const float sc = 0.17677669529663687f;   // 1/sqrt(32)
        p00 *= sc; p01 *= sc; p10 *= sc; p11 *= sc;
        float m0 = fmaxf(p00, p01), e00 = expf(p00 - m0), e01 = expf(p01 - m0);
        float i0 = 1.f / (e00 + e01);
        float m1 = fmaxf(p10, p11), e10 = expf(p10 - m1), e11 = expf(p11 - m1);
        float i1 = 1.f / (e10 + e11);
        #pragma unroll
        for (int dd = 0; dd < 16; ++dd) {
            int d = 16 * j + dd;
            float v0 = bf2f(row0[256 + d]), v1 = bf2f(row1[256 + d]);
            sm.t.xs_l[(2 * g4) * 136 + d]     = f2bf((e00 * v0 + e01 * v1) * i0);
            sm.t.xs_l[(2 * g4 + 1) * 136 + d] = f2bf((e10 * v0 + e11 * v1) * i1);
        }
    }
    __syncthreads();

    // ---- out-proj + mean over L + final LN: wave w owns 16 cols, rows 0..7 ----
    {
        floatx4 acc = {};
        const unsigned short* ap = sm.t.xs_l + l15 * 136 + 8 * q;
        #pragma unroll
        for (int kk = 0; kk < DDIM; kk += 32) {
            short8 A = *(const short8*)(ap + kk);
            short8 B = *(const short8*)(outw + (size_t)(16 * w + l15) * DDIM + kk + 8 * q);
            acc = __builtin_amdgcn_mfma_f32_16x16x32_bf16(A, B, acc, 0, 0, 0);
        }
        int gc = 16 * w + l15;
        float ob = out_b[gc];
        float av[2];
        float s2[2], sq2[2];
        #pragma unroll
        for (int rr = 0; rr < 2; ++rr) {
            float v = 0.5f * (acc[2 * rr] + acc[2 * rr + 1]) + ob;   // batch row 2q+rr
            av[rr] = v; s2[rr] = v; sq2[rr] = v * v;
        }
        #pragma unroll
        for (int rr = 0; rr < 2; ++rr)
            #pragma unroll
            for (int off2 = 8; off2 >= 1; off2 >>= 1) {
                s2[rr] += __shfl_xor(s2[rr], off2, 64);
                sq2[rr] += __shfl_xor(sq2[rr], off2, 64);
            }
        if (l15 == 0) {
            #pragma unroll
            for (int rr = 0; rr < 2; ++rr) {
                psum[w][2 * q + rr] = s2[rr];
                psq[w][2 * q + rr] = sq2[rr];
            }
        }
        __syncthreads();
        float g2 = fg[gc], bb = fb[gc];
        #pragma unroll
        for (int rr = 0; rr < 2; ++rr) {
            int idx = 2 * q + rr;
            float ssum = 0.f, ssq = 0.f;
            #pragma unroll
            for (int ww = 0; ww < 8; ++ww) { ssum += psum[ww][idx]; ssq += psq[ww][idx]; }
            float mean = ssum * (1.f / DDIM);
            float var = ssq * (1.f / DDIM) - mean * mean;
            outp[(size_t)(r0 + idx) * DDIM + gc] = (av[rr] - mean) * rsqrtf(var + 1e-5f) * g2 + bb;
        }
    }
}

extern "C" void kernel_launch(void* const* d_in, const int* in_sizes, int n_in,
                              void* d_out, int out_size, void* d_ws, size_t ws_size,
                              hipStream_t stream) {
    const int*   drug_idx = (const int*)d_in[0];
    const int*   adj_ent  = (const int*)d_in[1];
    const int*   adj_rel  = (const int*)d_in[2];
    const float* ew       = (const float*)d_in[3];
    const float* emb      = (const float*)d_in[4];
    const float* W_rgcn   = (const float*)d_in[5];
    const float* res_w    = (const float*)d_in[6];
    const float* res_b    = (const float*)d_in[7];
    const float* proj_w   = (const float*)d_in[8];
    const float* proj_b   = (const float*)d_in[9];
    const float* ln_g     = (const float*)d_in[10];
    const float* ln_b     = (const float*)d_in[11];
    const float* in_w     = (const float*)d_in[12];
    const float* in_b     = (const float*)d_in[13];
    const float* out_w    = (const float*)d_in[14];
    const float* out_b    = (const float*)d_in[15];
    const float* fg       = (const float*)d_in[16];
    const float* fb       = (const float*)d_in[17];
    float* outp = (float*)d_out;

    char* ws = (char*)d_ws;
    size_t off = 0;
    auto alloc = [&](size_t bytes) { size_t o = off; off = (off + bytes + 255) & ~(size_t)255; return o; };
    unsigned short* Wcat    = (unsigned short*)(ws + alloc((size_t)256 * 2048 * 2));
    unsigned short* resw    = (unsigned short*)(ws + alloc((size_t)2 * 128 * 128 * 2));
    unsigned short* projw   = (unsigned short*)(ws + alloc((size_t)2 * 128 * 128 * 2));
    unsigned short* inw     = (unsigned short*)(ws + alloc((size_t)384 * 128 * 2));
    unsigned short* outw    = (unsigned short*)(ws + alloc((size_t)128 * 128 * 2));

    hipLaunchKernelGGL(k_prep, dim3(256), dim3(256), 0, stream,
                       W_rgcn, res_w, proj_w, in_w, out_w,
                       Wcat, resw, projw, inw, outw);
    hipLaunchKernelGGL(k_fused, dim3(BBATCH / ROWS), dim3(512), 0, stream,
                       drug_idx, adj_ent, adj_rel, ew, emb,
                       Wcat, resw, projw, res_b, proj_b, ln_g, ln_b,
                       inw, in_b, outw, out_b, fg, fb, outp);
}

// Round 7
// 232.932 us; speedup vs baseline: 1.1243x; 1.1243x over previous
//
#include <hip/hip_runtime.h>
#include <math.h>

#define NRREL 16
#define DDIM 128
#define BBATCH 4096
#define SNBR 64
#define ROWS 16

typedef __attribute__((ext_vector_type(8))) short short8;
typedef __attribute__((ext_vector_type(4))) float floatx4;

__device__ __forceinline__ unsigned short f2bf(float f) {
    unsigned u = __builtin_bit_cast(unsigned, f);
    u += 0x7fffu + ((u >> 16) & 1u);
    return (unsigned short)(u >> 16);
}
__device__ __forceinline__ float bf2f(unsigned short u) {
    return __builtin_bit_cast(float, ((unsigned)u) << 16);
}

// ============ prep: weight conversion only (256 blocks) ============
extern "C" __global__ __launch_bounds__(256)
void k_prep(const float* __restrict__ W_rgcn,
            const float* __restrict__ res_w, const float* __restrict__ proj_w,
            const float* __restrict__ in_w, const float* __restrict__ out_w,
            unsigned short* __restrict__ Wcat, unsigned short* __restrict__ resw,
            unsigned short* __restrict__ projw, unsigned short* __restrict__ inw,
            unsigned short* __restrict__ outw)
{
    __shared__ float tileT[64 * 65];
    const int bid = blockIdx.x, t = threadIdx.x;

    if (bid < 128) {
        const int l = bid >> 6, rem = bid & 63;
        const int k0 = (rem >> 1) * 64, e0 = (rem & 1) * 64;
        #pragma unroll
        for (int i = 0; i < 4; ++i) {
            int flat = t + 256 * i;              // 64 k x 16 col4
            int k = flat >> 4, c = flat & 15;
            float4 v = *(const float4*)(W_rgcn + ((size_t)(l * 2048 + k0 + k)) * 128 + e0 + 4 * c);
            tileT[(4 * c + 0) * 65 + k] = v.x;
            tileT[(4 * c + 1) * 65 + k] = v.y;
            tileT[(4 * c + 2) * 65 + k] = v.z;
            tileT[(4 * c + 3) * 65 + k] = v.w;
        }
        __syncthreads();
        const int e = t >> 2, m = t & 3;
        #pragma unroll
        for (int half = 0; half < 2; ++half) {
            int kk = 16 * m + 8 * half;
            short8 o;
            #pragma unroll
            for (int j = 0; j < 8; ++j) o[j] = (short)f2bf(tileT[e * 65 + kk + j]);
            *(short8*)(Wcat + ((size_t)(l * 128 + e0 + e)) * 2048 + k0 + kk) = o;
        }
    } else {
        int j4 = ((bid - 128) * 256 + t) * 4;   // 131072 floats
        const float* src; unsigned short* dst; int off;
        if (j4 < 32768)       { src = res_w;  dst = resw;  off = j4; }
        else if (j4 < 65536)  { src = proj_w; dst = projw; off = j4 - 32768; }
        else if (j4 < 114688) { src = in_w;   dst = inw;   off = j4 - 65536; }
        else                  { src = out_w;  dst = outw;  off = j4 - 114688; }
        float4 v = *(const float4*)(src + off);
        ushort4 o = { f2bf(v.x), f2bf(v.y), f2bf(v.z), f2bf(v.w) };
        *(ushort4*)(dst + off) = o;
    }
}

// ====== fused, 16 rows/block, 256 blocks x 1024 thr (16 waves, 4/SIMD) ======
extern "C" __global__ __launch_bounds__(1024)
void k_fused(const int* __restrict__ drug, const int* __restrict__ adj_e,
             const int* __restrict__ adj_r, const float* __restrict__ ew,
             const float* __restrict__ emb,
             const unsigned short* __restrict__ Wcat,
             const unsigned short* __restrict__ resw, const unsigned short* __restrict__ projw,
             const float* __restrict__ res_b, const float* __restrict__ proj_b,
             const float* __restrict__ ln_g, const float* __restrict__ ln_b,
             const unsigned short* __restrict__ inw, const float* __restrict__ in_b,
             const unsigned short* __restrict__ outw, const float* __restrict__ out_b,
             const float* __restrict__ fg, const float* __restrict__ fb,
             float* __restrict__ outp)
{
    __shared__ union {
        struct { unsigned short preA[ROWS * 2056]; } a;   // 65.8 KB gather dest / msgs A
        struct {
            unsigned short h_b16[ROWS * 136];             // 4.3 KB
            unsigned short xs_l[2 * ROWS * 136];          // 8.7 KB
            unsigned short qkvl[2 * ROWS * 392];          // 25 KB
        } t;
    } sm;
    __shared__ float node_ln[ROWS * 132];                  // 8.4 KB
    __shared__ unsigned short node_b16[ROWS * 136];        // 4.3 KB
    __shared__ union {
        struct {
            int   cnt[ROWS][16];
            int   strt[ROWS][16];
            int   sperm[ROWS][64];
            float wperm[ROWS][64];
        } g;                                               // 10 KB
        float msum[ROWS * 260];                            // 16.6 KB
    } sg;
    __shared__ float psum[16][16], psq[16][16];

    const int t = threadIdx.x, w = t >> 6, lane = t & 63, l15 = lane & 15, q = lane >> 4;
    const int r0 = blockIdx.x * ROWS;

    // ---- phase A: 1 edge/thread (1024 = 16 rows x 64 nbrs); node rows into LDS ----
    const int erow = t >> 6, es = t & 63;
    int   ent0 = adj_e[(r0 + erow) * SNBR + es];
    float ewt0 = ew[(r0 + erow) * SNBR + es];
    int   rel0 = adj_r[(r0 + erow) * SNBR + es];
    if (t < 256) sg.g.cnt[t >> 4][t & 15] = 0;
    if (t < 512) {
        int rr = t >> 5, c = t & 31;         // 16 rows x 32 col4
        int di = drug[r0 + rr];
        float4 v = *(const float4*)(emb + (size_t)di * DDIM + 4 * c);
        *(float4*)(node_ln + rr * 132 + 4 * c) = v;
        ushort4 o = { f2bf(v.x), f2bf(v.y), f2bf(v.z), f2bf(v.w) };
        *(ushort4*)(node_b16 + rr * 136 + 4 * c) = o;
    }
    __syncthreads();

    // ---- phase B: count members per (row, rel) ----
    atomicAdd(&sg.g.cnt[erow][rel0], 1);
    __syncthreads();

    // ---- phase C: prefix sums (CSR starts) ----
    if (t < ROWS) {
        int a = 0;
        #pragma unroll
        for (int r = 0; r < NRREL; ++r) { sg.g.strt[t][r] = a; a += sg.g.cnt[t][r]; }
    }
    __syncthreads();

    // ---- phase D: place (entity, weight) bucket-sorted; strt becomes end ----
    {
        int pos0 = atomicAdd(&sg.g.strt[erow][rel0], 1);
        sg.g.sperm[erow][pos0] = ent0;
        sg.g.wperm[erow][pos0] = ewt0;
    }
    __syncthreads();

    // ---- phase E: accumulate preA; 4 units/thread, batch-8 loads in flight ----
    {
        #pragma unroll 1
        for (int i = 0; i < 4; ++i) {
            int u = t + 1024 * i;                // 16 rows x 16 rel x 16 g8 = 4096
            int row = u >> 8, rl = (u >> 4) & 15, g8 = u & 15;
            int n = sg.g.cnt[row][rl];
            int end = sg.g.strt[row][rl];
            int beg = end - n;
            float acc[8] = {0.f, 0.f, 0.f, 0.f, 0.f, 0.f, 0.f, 0.f};
            #pragma unroll 1
            for (int jb = beg; jb < end; jb += 8) {
                const float* pp[8]; float wq[8];
                #pragma unroll
                for (int u2 = 0; u2 < 8; ++u2) {
                    int live = (jb + u2 < end);
                    int j = live ? jb + u2 : beg;
                    wq[u2] = live ? sg.g.wperm[row][j] : 0.f;
                    pp[u2] = emb + (size_t)sg.g.sperm[row][j] * DDIM + 8 * g8;
                }
                float4 v0[8], v1[8];
                #pragma unroll
                for (int u2 = 0; u2 < 8; ++u2) {
                    v0[u2] = *(const float4*)pp[u2];
                    v1[u2] = *(const float4*)(pp[u2] + 4);
                }
                #pragma unroll
                for (int u2 = 0; u2 < 8; ++u2) {
                    acc[0] = fmaf(v0[u2].x, wq[u2], acc[0]); acc[1] = fmaf(v0[u2].y, wq[u2], acc[1]);
                    acc[2] = fmaf(v0[u2].z, wq[u2], acc[2]); acc[3] = fmaf(v0[u2].w, wq[u2], acc[3]);
                    acc[4] = fmaf(v1[u2].x, wq[u2], acc[4]); acc[5] = fmaf(v1[u2].y, wq[u2], acc[5]);
                    acc[6] = fmaf(v1[u2].z, wq[u2], acc[6]); acc[7] = fmaf(v1[u2].w, wq[u2], acc[7]);
                }
            }
            short8 o;
            #pragma unroll
            for (int jj = 0; jj < 8; ++jj) o[jj] = (short)f2bf(acc[jj]);
            *(short8*)(sm.a.preA + row * 2056 + rl * DDIM + 8 * g8) = o;
        }
    }
    __syncthreads();

    // ---- msgs = preA[16,2048] x Wcat^T[2048,256]; wave w owns 16 cols ----
    {
        floatx4 macc = {};
        const unsigned short* ap = sm.a.preA + l15 * 2056 + 8 * q;
        const unsigned short* bp = Wcat + (size_t)(16 * w + l15) * 2048 + 8 * q;
        #pragma unroll 8
        for (int k = 0; k < 2048; k += 32) {
            short8 A = *(const short8*)(ap + k);
            short8 B = *(const short8*)(bp + k);
            macc = __builtin_amdgcn_mfma_f32_16x16x32_bf16(A, B, macc, 0, 0, 0);
        }
        int gc = 16 * w + l15;
        #pragma unroll
        for (int r = 0; r < 4; ++r)
            sg.msum[(4 * q + r) * 260 + gc] = macc[r];
    }
    __syncthreads();          // preA dead; sm.t alive; gather scratch dead (msum alive)

    // ---- RGCN layers: waves 0..7 own cols 16w..16w+15; waves 8..15 barrier-only ----
    for (int l = 0; l < 2; ++l) {
        if (w < 8) {   // GEMM1: h = relu(node + msum_l + node x resw_l^T + res_b)
            const unsigned short* Bw = resw + (size_t)l * DDIM * DDIM;
            floatx4 acc = {};
            const unsigned short* ap = node_b16 + l15 * 136 + 8 * q;
            #pragma unroll
            for (int kk = 0; kk < DDIM; kk += 32) {
                short8 A = *(const short8*)(ap + kk);
                short8 B = *(const short8*)(Bw + (size_t)(16 * w + l15) * DDIM + kk + 8 * q);
                acc = __builtin_amdgcn_mfma_f32_16x16x32_bf16(A, B, acc, 0, 0, 0);
            }
            int gc = 16 * w + l15;
            float rb = res_b[l * DDIM + gc];
            #pragma unroll
            for (int r = 0; r < 4; ++r) {
                int lr = 4 * q + r;
                float v = acc[r] + rb + node_ln[lr * 132 + gc] + sg.msum[lr * 260 + l * DDIM + gc];
                sm.t.h_b16[lr * 136 + gc] = f2bf(v > 0.f ? v : 0.f);
            }
        }
        __syncthreads();
        {   // GEMM2 + LN
            float vv[4];
            int gc = 16 * w + l15;
            if (w < 8) {
                const unsigned short* Bw = projw + (size_t)l * DDIM * DDIM;
                floatx4 acc = {};
                const unsigned short* ap = sm.t.h_b16 + l15 * 136 + 8 * q;
                #pragma unroll
                for (int kk = 0; kk < DDIM; kk += 32) {
                    short8 A = *(const short8*)(ap + kk);
                    short8 B = *(const short8*)(Bw + (size_t)(16 * w + l15) * DDIM + kk + 8 * q);
                    acc = __builtin_amdgcn_mfma_f32_16x16x32_bf16(A, B, acc, 0, 0, 0);
                }
                float s4[4], sq4[4];
                float pb = proj_b[l * DDIM + gc];
                #pragma unroll
                for (int r = 0; r < 4; ++r) {
                    float v = acc[r] + pb + node_ln[(4 * q + r) * 132 + gc];
                    vv[r] = v; s4[r] = v; sq4[r] = v * v;
                }
                #pragma unroll
                for (int r = 0; r < 4; ++r)
                    #pragma unroll
                    for (int off2 = 8; off2 >= 1; off2 >>= 1) {
                        s4[r] += __shfl_xor(s4[r], off2, 64);
                        sq4[r] += __shfl_xor(sq4[r], off2, 64);
                    }
                if (l15 == 0) {
                    #pragma unroll
                    for (int r = 0; r < 4; ++r) {
                        psum[w][4 * q + r] = s4[r];
                        psq[w][4 * q + r] = sq4[r];
                    }
                }
            }
            __syncthreads();
            if (w < 8) {
                float g2 = ln_g[l * DDIM + gc], bb = ln_b[l * DDIM + gc];
                #pragma unroll
                for (int r = 0; r < 4; ++r) {
                    int lr = 4 * q + r;
                    float ssum = 0.f, ssq = 0.f;
                    #pragma unroll
                    for (int ww = 0; ww < 8; ++ww) { ssum += psum[ww][lr]; ssq += psq[ww][lr]; }
                    float mean = ssum * (1.f / DDIM);
                    float var = ssq * (1.f / DDIM) - mean * mean;
                    float val = (vv[r] - mean) * rsqrtf(var + 1e-5f) * g2 + bb;
                    node_ln[lr * 132 + gc] = val;
                    unsigned short ub = f2bf(val);
                    node_b16[lr * 136 + gc] = ub;
                    sm.t.xs_l[(2 * lr + l) * 136 + gc] = ub;
                }
            }
            __syncthreads();
        }
    }

    // ---- qkv: waves 0..11 -> xs rows 16*(w&1).., cols 64*(w>>1).. ----
    if (w < 12) {
        floatx4 acc[4] = {};
        const unsigned short* ap = sm.t.xs_l + (16 * (w & 1) + l15) * 136 + 8 * q;
        #pragma unroll
        for (int kk = 0; kk < DDIM; kk += 32) {
            short8 A = *(const short8*)(ap + kk);
            #pragma unroll
            for (int ni = 0; ni < 4; ++ni) {
                short8 B = *(const short8*)(inw + (size_t)(64 * (w >> 1) + ni * 16 + l15) * DDIM + kk + 8 * q);
                acc[ni] = __builtin_amdgcn_mfma_f32_16x16x32_bf16(A, B, acc[ni], 0, 0, 0);
            }
        }
        #pragma unroll
        for (int ni = 0; ni < 4; ++ni) {
            int gc = 64 * (w >> 1) + ni * 16 + l15;
            float ib = in_b[gc];
            #pragma unroll
            for (int r = 0; r < 4; ++r)
                sm.t.qkvl[(16 * (w & 1) + 4 * q + r) * 392 + gc] = f2bf(acc[ni][r] + ib);
        }
    }
    __syncthreads();

    // ---- attention: 16 batch rows x 8 lanes (t < 128) ----
    if (t < 128) {
        int g4 = t >> 3, j = t & 7;
        const unsigned short* row0 = sm.t.qkvl + (2 * g4) * 392;
        const unsigned short* row1 = row0 + 392;
        float p00 = 0.f, p01 = 0.f, p10 = 0.f, p11 = 0.f;
        #pragma unroll
        for (int dd = 0; dd < 16; ++dd) {
            int d = 16 * j + dd;
            float q0 = bf2f(row0[d]), k0 = bf2f(row0[128 + d]);
            float q1 = bf2f(row1[d]), k1 = bf2f(row1[128 + d]);
            p00 = fmaf(q0, k0, p00); p01 = fmaf(q0, k1, p01);
            p10 = fmaf(q1, k0, p10); p11 = fmaf(q1, k1, p11);
        }
        p00 += __shfl_xor(p00, 1, 64); p01 += __shfl_xor(p01, 1, 64);
        p10 += __shfl_xor(p10, 1, 64); p11 += __shfl_xor(p11, 1, 64);
        const float sc = 0.17677669529663687f;   // 1/sqrt(32)
        p00 *= sc; p01 *= sc; p10 *= sc; p11 *= sc;
        float m0 = fmaxf(p00, p01), e00 = expf(p00 - m0), e01 = expf(p01 - m0);
        float i0 = 1.f / (e00 + e01);
        float m1 = fmaxf(p10, p11), e10 = expf(p10 - m1), e11 = expf(p11 - m1);
        float i1 = 1.f / (e10 + e11);
        #pragma unroll
        for (int dd = 0; dd < 16; ++dd) {
            int d = 16 * j + dd;
            float v0 = bf2f(row0[256 + d]), v1 = bf2f(row1[256 + d]);
            sm.t.xs_l[(2 * g4) * 136 + d]     = f2bf((e00 * v0 + e01 * v1) * i0);
            sm.t.xs_l[(2 * g4 + 1) * 136 + d] = f2bf((e10 * v0 + e11 * v1) * i1);
        }
    }
    __syncthreads();

    // ---- out-proj + mean over L + final LN: wave w -> rows 16*(w&1), cols 16*(w>>1) --
    {
        floatx4 acc = {};
        const unsigned short* ap = sm.t.xs_l + (16 * (w & 1) + l15) * 136 + 8 * q;
        #pragma unroll
        for (int kk = 0; kk < DDIM; kk += 32) {
            short8 A = *(const short8*)(ap + kk);
            short8 B = *(const short8*)(outw + (size_t)(16 * (w >> 1) + l15) * DDIM + kk + 8 * q);
            acc = __builtin_amdgcn_mfma_f32_16x16x32_bf16(A, B, acc, 0, 0, 0);
        }
        int gc = 16 * (w >> 1) + l15;
        float ob = out_b[gc];
        float av[2];
        float s2[2], sq2[2];
        #pragma unroll
        for (int rr = 0; rr < 2; ++rr) {
            float v = 0.5f * (acc[2 * rr] + acc[2 * rr + 1]) + ob;   // local row 2q+rr
            av[rr] = v; s2[rr] = v; sq2[rr] = v * v;
        }
        #pragma unroll
        for (int rr = 0; rr < 2; ++rr)
            #pragma unroll
            for (int off2 = 8; off2 >= 1; off2 >>= 1) {
                s2[rr] += __shfl_xor(s2[rr], off2, 64);
                sq2[rr] += __shfl_xor(sq2[rr], off2, 64);
            }
        if (l15 == 0) {
            #pragma unroll
            for (int rr = 0; rr < 2; ++rr) {
                psum[w][2 * q + rr] = s2[rr];
                psq[w][2 * q + rr] = sq2[rr];
            }
        }
        __syncthreads();
        float g2 = fg[gc], bb = fb[gc];
        #pragma unroll
        for (int rr = 0; rr < 2; ++rr) {
            int idx = 2 * q + rr;
            float ssum = 0.f, ssq = 0.f;
            #pragma unroll
            for (int ww = 0; ww < 8; ++ww) {
                ssum += psum[2 * ww + (w & 1)][idx];
                ssq  += psq[2 * ww + (w & 1)][idx];
            }
            float mean = ssum * (1.f / DDIM);
            float var = ssq * (1.f / DDIM) - mean * mean;
            outp[(size_t)(r0 + 8 * (w & 1) + idx) * DDIM + gc] =
                (av[rr] - mean) * rsqrtf(var + 1e-5f) * g2 + bb;
        }
    }
}

extern "C" void kernel_launch(void* const* d_in, const int* in_sizes, int n_in,
                              void* d_out, int out_size, void* d_ws, size_t ws_size,
                              hipStream_t stream) {
    const int*   drug_idx = (const int*)d_in[0];
    const int*   adj_ent  = (const int*)d_in[1];
    const int*   adj_rel  = (const int*)d_in[2];
    const float* ew       = (const float*)d_in[3];
    const float* emb      = (const float*)d_in[4];
    const float* W_rgcn   = (const float*)d_in[5];
    const float* res_w    = (const float*)d_in[6];
    const float* res_b    = (const float*)d_in[7];
    const float* proj_w   = (const float*)d_in[8];
    const float* proj_b   = (const float*)d_in[9];
    const float* ln_g     = (const float*)d_in[10];
    const float* ln_b     = (const float*)d_in[11];
    const float* in_w     = (const float*)d_in[12];
    const float* in_b     = (const float*)d_in[13];
    const float* out_w    = (const float*)d_in[14];
    const float* out_b    = (const float*)d_in[15];
    const float* fg       = (const float*)d_in[16];
    const float* fb       = (const float*)d_in[17];
    float* outp = (float*)d_out;

    char* ws = (char*)d_ws;
    size_t off = 0;
    auto alloc = [&](size_t bytes) { size_t o = off; off = (off + bytes + 255) & ~(size_t)255; return o; };
    unsigned short* Wcat    = (unsigned short*)(ws + alloc((size_t)256 * 2048 * 2));
    unsigned short* resw    = (unsigned short*)(ws + alloc((size_t)2 * 128 * 128 * 2));
    unsigned short* projw   = (unsigned short*)(ws + alloc((size_t)2 * 128 * 128 * 2));
    unsigned short* inw     = (unsigned short*)(ws + alloc((size_t)384 * 128 * 2));
    unsigned short* outw    = (unsigned short*)(ws + alloc((size_t)128 * 128 * 2));

    hipLaunchKernelGGL(k_prep, dim3(256), dim3(256), 0, stream,
                       W_rgcn, res_w, proj_w, in_w, out_w,
                       Wcat, resw, projw, inw, outw);
    hipLaunchKernelGGL(k_fused, dim3(BBATCH / ROWS), dim3(1024), 0, stream,
                       drug_idx, adj_ent, adj_rel, ew, emb,
                       Wcat, resw, projw, res_b, proj_b, ln_g, ln_b,
                       inw, in_b, outw, out_b, fg, fb, outp);
}

// Round 9
// 230.336 us; speedup vs baseline: 1.1369x; 1.0113x over previous
//
#include <hip/hip_runtime.h>
#include <math.h>

#define NRREL 16
#define DDIM 128
#define BBATCH 4096
#define SNBR 64
#define ROWS 16

typedef __attribute__((ext_vector_type(8))) short short8;
typedef __attribute__((ext_vector_type(4))) float floatx4;

__device__ __forceinline__ unsigned short f2bf(float f) {
    unsigned u = __builtin_bit_cast(unsigned, f);
    u += 0x7fffu + ((u >> 16) & 1u);
    return (unsigned short)(u >> 16);
}
__device__ __forceinline__ float bf2f(unsigned short u) {
    return __builtin_bit_cast(float, ((unsigned)u) << 16);
}

// ============ prep: weight conversion only (256 blocks) ============
extern "C" __global__ __launch_bounds__(256)
void k_prep(const float* __restrict__ W_rgcn,
            const float* __restrict__ res_w, const float* __restrict__ proj_w,
            const float* __restrict__ in_w, const float* __restrict__ out_w,
            unsigned short* __restrict__ Wcat, unsigned short* __restrict__ resw,
            unsigned short* __restrict__ projw, unsigned short* __restrict__ inw,
            unsigned short* __restrict__ outw)
{
    __shared__ float tileT[64 * 65];
    const int bid = blockIdx.x, t = threadIdx.x;

    if (bid < 128) {
        const int l = bid >> 6, rem = bid & 63;
        const int k0 = (rem >> 1) * 64, e0 = (rem & 1) * 64;
        #pragma unroll
        for (int i = 0; i < 4; ++i) {
            int flat = t + 256 * i;              // 64 k x 16 col4
            int k = flat >> 4, c = flat & 15;
            float4 v = *(const float4*)(W_rgcn + ((size_t)(l * 2048 + k0 + k)) * 128 + e0 + 4 * c);
            tileT[(4 * c + 0) * 65 + k] = v.x;
            tileT[(4 * c + 1) * 65 + k] = v.y;
            tileT[(4 * c + 2) * 65 + k] = v.z;
            tileT[(4 * c + 3) * 65 + k] = v.w;
        }
        __syncthreads();
        const int e = t >> 2, m = t & 3;
        #pragma unroll
        for (int half = 0; half < 2; ++half) {
            int kk = 16 * m + 8 * half;
            short8 o;
            #pragma unroll
            for (int j = 0; j < 8; ++j) o[j] = (short)f2bf(tileT[e * 65 + kk + j]);
            *(short8*)(Wcat + ((size_t)(l * 128 + e0 + e)) * 2048 + k0 + kk) = o;
        }
    } else {
        int j4 = ((bid - 128) * 256 + t) * 4;   // 131072 floats
        const float* src; unsigned short* dst; int off;
        if (j4 < 32768)       { src = res_w;  dst = resw;  off = j4; }
        else if (j4 < 65536)  { src = proj_w; dst = projw; off = j4 - 32768; }
        else if (j4 < 114688) { src = in_w;   dst = inw;   off = j4 - 65536; }
        else                  { src = out_w;  dst = outw;  off = j4 - 114688; }
        float4 v = *(const float4*)(src + off);
        ushort4 o = { f2bf(v.x), f2bf(v.y), f2bf(v.z), f2bf(v.w) };
        *(ushort4*)(dst + off) = o;
    }
}

// ====== fused, 16 rows/block, 256 blocks x 1024 thr; wave-per-row edge streaming ======
extern "C" __global__ __launch_bounds__(1024)
void k_fused(const int* __restrict__ drug, const int* __restrict__ adj_e,
             const int* __restrict__ adj_r, const float* __restrict__ ew,
             const float* __restrict__ emb,
             const unsigned short* __restrict__ Wcat,
             const unsigned short* __restrict__ resw, const unsigned short* __restrict__ projw,
             const float* __restrict__ res_b, const float* __restrict__ proj_b,
             const float* __restrict__ ln_g, const float* __restrict__ ln_b,
             const unsigned short* __restrict__ inw, const float* __restrict__ in_b,
             const unsigned short* __restrict__ outw, const float* __restrict__ out_b,
             const float* __restrict__ fg, const float* __restrict__ fb,
             float* __restrict__ outp)
{
    __shared__ union {
        struct { unsigned short preA[ROWS * 2056]; } a;   // 65.8 KB gather dest / msgs A
        struct {
            unsigned short h_b16[ROWS * 136];             // 4.3 KB
            unsigned short xs_l[2 * ROWS * 136];          // 8.7 KB
            unsigned short qkvl[2 * ROWS * 392];          // 25 KB
        } t;
    } sm;
    __shared__ float node_ln[ROWS * 132];                  // 8.4 KB
    __shared__ unsigned short node_b16[ROWS * 136];        // 4.3 KB
    __shared__ union {
        struct {
            int   cnt[ROWS][16];
            int   strt[ROWS][16];
            int   sperm[ROWS][64];
            float wperm[ROWS][64];
            int   relperm[ROWS][64];
        } g;                                               // 14 KB
        float msum[ROWS * 260];                            // 16.6 KB
    } sg;
    __shared__ float psum[16][16], psq[16][16];

    const int t = threadIdx.x, w = t >> 6, lane = t & 63, l15 = lane & 15, q = lane >> 4;
    const int r0 = blockIdx.x * ROWS;

    // ---- phase A: 1 edge/thread (1024 = 16 rows x 64 nbrs); node rows into LDS ----
    const int erow = t >> 6, es = t & 63;
    int   ent0 = adj_e[(r0 + erow) * SNBR + es];
    float ewt0 = ew[(r0 + erow) * SNBR + es];
    int   rel0 = adj_r[(r0 + erow) * SNBR + es];
    if (t < 256) sg.g.cnt[t >> 4][t & 15] = 0;
    if (t < 512) {
        int rr = t >> 5, c = t & 31;         // 16 rows x 32 col4
        int di = drug[r0 + rr];
        float4 v = *(const float4*)(emb + (size_t)di * DDIM + 4 * c);
        *(float4*)(node_ln + rr * 132 + 4 * c) = v;
        ushort4 o = { f2bf(v.x), f2bf(v.y), f2bf(v.z), f2bf(v.w) };
        *(ushort4*)(node_b16 + rr * 136 + 4 * c) = o;
    }
    __syncthreads();

    // ---- phase B: count members per (row, rel) ----
    atomicAdd(&sg.g.cnt[erow][rel0], 1);
    __syncthreads();

    // ---- phase C: prefix sums (CSR starts) ----
    if (t < ROWS) {
        int a = 0;
        #pragma unroll
        for (int r = 0; r < NRREL; ++r) { sg.g.strt[t][r] = a; a += sg.g.cnt[t][r]; }
    }
    __syncthreads();

    // ---- phase D: place (entity, weight, rel) bucket-sorted ----
    {
        int pos0 = atomicAdd(&sg.g.strt[erow][rel0], 1);
        sg.g.sperm[erow][pos0]   = ent0;
        sg.g.wperm[erow][pos0]   = ewt0;
        sg.g.relperm[erow][pos0] = rel0;
    }
    __syncthreads();

    // ---- phase E: wave w streams row w's 64 sorted edges; lane owns 8 B of the row ----
    {
        const int row = w;
        // zero preA slices for empty buckets (disjoint from streamed buckets -> no race)
        if (t < 256) {
            int rr = t >> 4, rl = t & 15;
            if (sg.g.cnt[rr][rl] == 0) {
                short8 z = {};
                #pragma unroll
                for (int ii = 0; ii < 16; ++ii)
                    *(short8*)(sm.a.preA + rr * 2056 + rl * DDIM + 8 * ii) = z;
            }
        }
        const float* embl = emb + 2 * lane;
        unsigned short* prow = sm.a.preA + row * 2056 + 2 * lane;
        float a0 = 0.f, a1 = 0.f;
        int prev = -1;
        // preload group 0
        int   e0 = sg.g.sperm[row][0], e1 = sg.g.sperm[row][1],
              e2 = sg.g.sperm[row][2], e3 = sg.g.sperm[row][3];
        float w0 = sg.g.wperm[row][0], w1 = sg.g.wperm[row][1],
              w2 = sg.g.wperm[row][2], w3 = sg.g.wperm[row][3];
        int   c0 = sg.g.relperm[row][0], c1 = sg.g.relperm[row][1],
              c2 = sg.g.relperm[row][2], c3 = sg.g.relperm[row][3];
        float2 v0 = *(const float2*)(embl + (size_t)e0 * DDIM);
        float2 v1 = *(const float2*)(embl + (size_t)e1 * DDIM);
        float2 v2 = *(const float2*)(embl + (size_t)e2 * DDIM);
        float2 v3 = *(const float2*)(embl + (size_t)e3 * DDIM);
        #pragma unroll 1
        for (int j = 0; j < SNBR; j += 4) {
            // prefetch next group (2-stage pipeline: 8 rows in flight/wave)
            float2 n0 = {}, n1 = {}, n2 = {}, n3 = {};
            float nw0 = 0.f, nw1 = 0.f, nw2 = 0.f, nw3 = 0.f;
            int nc0 = 0, nc1 = 0, nc2 = 0, nc3 = 0;
            if (j + 4 < SNBR) {
                int f0 = sg.g.sperm[row][j + 4], f1 = sg.g.sperm[row][j + 5],
                    f2 = sg.g.sperm[row][j + 6], f3 = sg.g.sperm[row][j + 7];
                nw0 = sg.g.wperm[row][j + 4]; nw1 = sg.g.wperm[row][j + 5];
                nw2 = sg.g.wperm[row][j + 6]; nw3 = sg.g.wperm[row][j + 7];
                nc0 = sg.g.relperm[row][j + 4]; nc1 = sg.g.relperm[row][j + 5];
                nc2 = sg.g.relperm[row][j + 6]; nc3 = sg.g.relperm[row][j + 7];
                n0 = *(const float2*)(embl + (size_t)f0 * DDIM);
                n1 = *(const float2*)(embl + (size_t)f1 * DDIM);
                n2 = *(const float2*)(embl + (size_t)f2 * DDIM);
                n3 = *(const float2*)(embl + (size_t)f3 * DDIM);
            }
            // process current group: cond-reset on rel change, fma, store running sum
            {
                bool ch = (c0 != prev);
                a0 = ch ? 0.f : a0; a1 = ch ? 0.f : a1;
                a0 = fmaf(v0.x, w0, a0); a1 = fmaf(v0.y, w0, a1);
                unsigned pk = (unsigned)f2bf(a0) | ((unsigned)f2bf(a1) << 16);
                *(unsigned*)(prow + (size_t)c0 * DDIM) = pk; prev = c0;
            }
            {
                bool ch = (c1 != prev);
                a0 = ch ? 0.f : a0; a1 = ch ? 0.f : a1;
                a0 = fmaf(v1.x, w1, a0); a1 = fmaf(v1.y, w1, a1);
                unsigned pk = (unsigned)f2bf(a0) | ((unsigned)f2bf(a1) << 16);
                *(unsigned*)(prow + (size_t)c1 * DDIM) = pk; prev = c1;
            }
            {
                bool ch = (c2 != prev);
                a0 = ch ? 0.f : a0; a1 = ch ? 0.f : a1;
                a0 = fmaf(v2.x, w2, a0); a1 = fmaf(v2.y, w2, a1);
                unsigned pk = (unsigned)f2bf(a0) | ((unsigned)f2bf(a1) << 16);
                *(unsigned*)(prow + (size_t)c2 * DDIM) = pk; prev = c2;
            }
            {
                bool ch = (c3 != prev);
                a0 = ch ? 0.f : a0; a1 = ch ? 0.f : a1;
                a0 = fmaf(v3.x, w3, a0); a1 = fmaf(v3.y, w3, a1);
                unsigned pk = (unsigned)f2bf(a0) | ((unsigned)f2bf(a1) << 16);
                *(unsigned*)(prow + (size_t)c3 * DDIM) = pk; prev = c3;
            }
            v0 = n0; v1 = n1; v2 = n2; v3 = n3;
            w0 = nw0; w1 = nw1; w2 = nw2; w3 = nw3;
            c0 = nc0; c1 = nc1; c2 = nc2; c3 = nc3;
        }
    }
    __syncthreads();

    // ---- msgs = preA[16,2048] x Wcat^T[2048,256]; wave w owns 16 cols ----
    {
        floatx4 macc = {};
        const unsigned short* ap = sm.a.preA + l15 * 2056 + 8 * q;
        const unsigned short* bp = Wcat + (size_t)(16 * w + l15) * 2048 + 8 * q;
        #pragma unroll 8
        for (int k = 0; k < 2048; k += 32) {
            short8 A = *(const short8*)(ap + k);
            short8 B = *(const short8*)(bp + k);
            macc = __builtin_amdgcn_mfma_f32_16x16x32_bf16(A, B, macc, 0, 0, 0);
        }
        int gc = 16 * w + l15;
        #pragma unroll
        for (int r = 0; r < 4; ++r)
            sg.msum[(4 * q + r) * 260 + gc] = macc[r];
    }
    __syncthreads();          // preA dead; sm.t alive; gather scratch dead (msum alive)

    // ---- RGCN layers: waves 0..7 own cols 16w..16w+15; waves 8..15 barrier-only ----
    for (int l = 0; l < 2; ++l) {
        if (w < 8) {   // GEMM1: h = relu(node + msum_l + node x resw_l^T + res_b)
            const unsigned short* Bw = resw + (size_t)l * DDIM * DDIM;
            floatx4 acc = {};
            const unsigned short* ap = node_b16 + l15 * 136 + 8 * q;
            #pragma unroll
            for (int kk = 0; kk < DDIM; kk += 32) {
                short8 A = *(const short8*)(ap + kk);
                short8 B = *(const short8*)(Bw + (size_t)(16 * w + l15) * DDIM + kk + 8 * q);
                acc = __builtin_amdgcn_mfma_f32_16x16x32_bf16(A, B, acc, 0, 0, 0);
            }
            int gc = 16 * w + l15;
            float rb = res_b[l * DDIM + gc];
            #pragma unroll
            for (int r = 0; r < 4; ++r) {
                int lr = 4 * q + r;
                float v = acc[r] + rb + node_ln[lr * 132 + gc] + sg.msum[lr * 260 + l * DDIM + gc];
                sm.t.h_b16[lr * 136 + gc] = f2bf(v > 0.f ? v : 0.f);
            }
        }
        __syncthreads();
        {   // GEMM2 + LN
            float vv[4];
            int gc = 16 * w + l15;
            if (w < 8) {
                const unsigned short* Bw = projw + (size_t)l * DDIM * DDIM;
                floatx4 acc = {};
                const unsigned short* ap = sm.t.h_b16 + l15 * 136 + 8 * q;
                #pragma unroll
                for (int kk = 0; kk < DDIM; kk += 32) {
                    short8 A = *(const short8*)(ap + kk);
                    short8 B = *(const short8*)(Bw + (size_t)(16 * w + l15) * DDIM + kk + 8 * q);
                    acc = __builtin_amdgcn_mfma_f32_16x16x32_bf16(A, B, acc, 0, 0, 0);
                }
                float s4[4], sq4[4];
                float pb = proj_b[l * DDIM + gc];
                #pragma unroll
                for (int r = 0; r < 4; ++r) {
                    float v = acc[r] + pb + node_ln[(4 * q + r) * 132 + gc];
                    vv[r] = v; s4[r] = v; sq4[r] = v * v;
                }
                #pragma unroll
                for (int r = 0; r < 4; ++r)
                    #pragma unroll
                    for (int off2 = 8; off2 >= 1; off2 >>= 1) {
                        s4[r] += __shfl_xor(s4[r], off2, 64);
                        sq4[r] += __shfl_xor(sq4[r], off2, 64);
                    }
                if (l15 == 0) {
                    #pragma unroll
                    for (int r = 0; r < 4; ++r) {
                        psum[w][4 * q + r] = s4[r];
                        psq[w][4 * q + r] = sq4[r];
                    }
                }
            }
            __syncthreads();
            if (w < 8) {
                float g2 = ln_g[l * DDIM + gc], bb = ln_b[l * DDIM + gc];
                #pragma unroll
                for (int r = 0; r < 4; ++r) {
                    int lr = 4 * q + r;
                    float ssum = 0.f, ssq = 0.f;
                    #pragma unroll
                    for (int ww = 0; ww < 8; ++ww) { ssum += psum[ww][lr]; ssq += psq[ww][lr]; }
                    float mean = ssum * (1.f / DDIM);
                    float var = ssq * (1.f / DDIM) - mean * mean;
                    float val = (vv[r] - mean) * rsqrtf(var + 1e-5f) * g2 + bb;
                    node_ln[lr * 132 + gc] = val;
                    unsigned short ub = f2bf(val);
                    node_b16[lr * 136 + gc] = ub;
                    sm.t.xs_l[(2 * lr + l) * 136 + gc] = ub;
                }
            }
            __syncthreads();
        }
    }

    // ---- qkv: waves 0..11 -> xs rows 16*(w&1).., cols 64*(w>>1).. ----
    if (w < 12) {
        floatx4 acc[4] = {};
        const unsigned short* ap = sm.t.xs_l + (16 * (w & 1) + l15) * 136 + 8 * q;
        #pragma unroll
        for (int kk = 0; kk < DDIM; kk += 32) {
            short8 A = *(const short8*)(ap + kk);
            #pragma unroll
            for (int ni = 0; ni < 4; ++ni) {
                short8 B = *(const short8*)(inw + (size_t)(64 * (w >> 1) + ni * 16 + l15) * DDIM + kk + 8 * q);
                acc[ni] = __builtin_amdgcn_mfma_f32_16x16x32_bf16(A, B, acc[ni], 0, 0, 0);
            }
        }
        #pragma unroll
        for (int ni = 0; ni < 4; ++ni) {
            int gc = 64 * (w >> 1) + ni * 16 + l15;
            float ib = in_b[gc];
            #pragma unroll
            for (int r = 0; r < 4; ++r)
                sm.t.qkvl[(16 * (w & 1) + 4 * q + r) * 392 + gc] = f2bf(acc[ni][r] + ib);
        }
    }
    __syncthreads();

    // ---- attention: 16 batch rows x 8 lanes (t < 128) ----
    if (t < 128) {
        int g4 = t >> 3, j = t & 7;
        const unsigned short* row0 = sm.t.qkvl + (2 * g4) * 392;
        const unsigned short* row1 = row0 + 392;
        float p00 = 0.f, p01 = 0.f, p10 = 0.f, p11 = 0.f;
        #pragma unroll
        for (int dd = 0; dd < 16; ++dd) {
            int d = 16 * j + dd;
            float q0 = bf2f(row0[d]), k0 = bf2f(row0[128 + d]);
            float q1 = bf2f(row1[d]), k1 = bf2f(row1[128 + d]);
            p00 = fmaf(q0, k0, p00); p01 = fmaf(q0, k1, p01);
            p10 = fmaf(q1, k0, p10); p11 = fmaf(q1, k1, p11);
        }
        p00 += __shfl_xor(p00, 1, 64); p01 += __shfl_xor(p01, 1, 64);
        p10 += __shfl_xor(p10, 1, 64); p11 += __shfl_xor(p11, 1, 64);
        const float sc = 0.17677669529663687f;   // 1/sqrt(32)
        p00 *= sc; p01 *= sc; p10 *= sc; p11 *= sc;
        float m0 = fmaxf(p00, p01), e00 = expf(p00 - m0), e01 = expf(p01 - m0);
        float i0 = 1.f / (e00 + e01);
        float m1 = fmaxf(p10, p11), e10 = expf(p10 - m1), e11 = expf(p11 - m1);
        float i1 = 1.f / (e10 + e11);
        #pragma unroll
        for (int dd = 0; dd < 16; ++dd) {
            int d = 16 * j + dd;
            float v0 = bf2f(row0[256 + d]), v1 = bf2f(row1[256 + d]);
            sm.t.xs_l[(2 * g4) * 136 + d]     = f2bf((e00 * v0 + e01 * v1) * i0);
            sm.t.xs_l[(2 * g4 + 1) * 136 + d] = f2bf((e10 * v0 + e11 * v1) * i1);
        }
    }
    __syncthreads();

    // ---- out-proj + mean over L + final LN: wave w -> rows 16*(w&1), cols 16*(w>>1) --
    {
        floatx4 acc = {};
        const unsigned short* ap = sm.t.xs_l + (16 * (w & 1) + l15) * 136 + 8 * q;
        #pragma unroll
        for (int kk = 0; kk < DDIM; kk += 32) {
            short8 A = *(const short8*)(ap + kk);
            short8 B = *(const short8*)(outw + (size_t)(16 * (w >> 1) + l15) * DDIM + kk + 8 * q);
            acc = __builtin_amdgcn_mfma_f32_16x16x32_bf16(A, B, acc, 0, 0, 0);
        }
        int gc = 16 * (w >> 1) + l15;
        float ob = out_b[gc];
        float av[2];
        float s2[2], sq2[2];
        #pragma unroll
        for (int rr = 0; rr < 2; ++rr) {
            float v = 0.5f * (acc[2 * rr] + acc[2 * rr + 1]) + ob;   // local row 2q+rr
            av[rr] = v; s2[rr] = v; sq2[rr] = v * v;
        }
        #pragma unroll
        for (int rr = 0; rr < 2; ++rr)
            #pragma unroll
            for (int off2 = 8; off2 >= 1; off2 >>= 1) {
                s2[rr] += __shfl_xor(s2[rr], off2, 64);
                sq2[rr] += __shfl_xor(sq2[rr], off2, 64);
            }
        if (l15 == 0) {
            #pragma unroll
            for (int rr = 0; rr < 2; ++rr) {
                psum[w][2 * q + rr] = s2[rr];
                psq[w][2 * q + rr] = sq2[rr];
            }
        }
        __syncthreads();
        float g2 = fg[gc], bb = fb[gc];
        #pragma unroll
        for (int rr = 0; rr < 2; ++rr) {
            int idx = 2 * q + rr;
            float ssum = 0.f, ssq = 0.f;
            #pragma unroll
            for (int ww = 0; ww < 8; ++ww) {
                ssum += psum[2 * ww + (w & 1)][idx];
                ssq  += psq[2 * ww + (w & 1)][idx];
            }
            float mean = ssum * (1.f / DDIM);
            float var = ssq * (1.f / DDIM) - mean * mean;
            outp[(size_t)(r0 + 8 * (w & 1) + idx) * DDIM + gc] =
                (av[rr] - mean) * rsqrtf(var + 1e-5f) * g2 + bb;
        }
    }
}

extern "C" void kernel_launch(void* const* d_in, const int* in_sizes, int n_in,
                              void* d_out, int out_size, void* d_ws, size_t ws_size,
                              hipStream_t stream) {
    const int*   drug_idx = (const int*)d_in[0];
    const int*   adj_ent  = (const int*)d_in[1];
    const int*   adj_rel  = (const int*)d_in[2];
    const float* ew       = (const float*)d_in[3];
    const float* emb      = (const float*)d_in[4];
    const float* W_rgcn   = (const float*)d_in[5];
    const float* res_w    = (const float*)d_in[6];
    const float* res_b    = (const float*)d_in[7];
    const float* proj_w   = (const float*)d_in[8];
    const float* proj_b   = (const float*)d_in[9];
    const float* ln_g     = (const float*)d_in[10];
    const float* ln_b     = (const float*)d_in[11];
    const float* in_w     = (const float*)d_in[12];
    const float* in_b     = (const float*)d_in[13];
    const float* out_w    = (const float*)d_in[14];
    const float* out_b    = (const float*)d_in[15];
    const float* fg       = (const float*)d_in[16];
    const float* fb       = (const float*)d_in[17];
    float* outp = (float*)d_out;

    char* ws = (char*)d_ws;
    size_t off = 0;
    auto alloc = [&](size_t bytes) { size_t o = off; off = (off + bytes + 255) & ~(size_t)255; return o; };
    unsigned short* Wcat    = (unsigned short*)(ws + alloc((size_t)256 * 2048 * 2));
    unsigned short* resw    = (unsigned short*)(ws + alloc((size_t)2 * 128 * 128 * 2));
    unsigned short* projw   = (unsigned short*)(ws + alloc((size_t)2 * 128 * 128 * 2));
    unsigned short* inw     = (unsigned short*)(ws + alloc((size_t)384 * 128 * 2));
    unsigned short* outw    = (unsigned short*)(ws + alloc((size_t)128 * 128 * 2));

    hipLaunchKernelGGL(k_prep, dim3(256), dim3(256), 0, stream,
                       W_rgcn, res_w, proj_w, in_w, out_w,
                       Wcat, resw, projw, inw, outw);
    hipLaunchKernelGGL(k_fused, dim3(BBATCH / ROWS), dim3(1024), 0, stream,
                       drug_idx, adj_ent, adj_rel, ew, emb,
                       Wcat, resw, projw, res_b, proj_b, ln_g, ln_b,
                       inw, in_b, outw, out_b, fg, fb, outp);
}